// Round 7
// baseline (1371.923 us; speedup 1.0000x reference)
//
#include <hip/hip_runtime.h>

#define Bq 2
#define Hh 8
#define Ss 512
#define HD 64
#define DIM 512

using f32x4   = __attribute__((ext_vector_type(4))) float;
using bf16x8s = __attribute__((ext_vector_type(8))) short;
typedef _Float16 f16x8 __attribute__((ext_vector_type(8)));

__device__ __forceinline__ float bf2f(unsigned short u) {
    return __uint_as_float(((unsigned int)u) << 16);
}
__device__ __forceinline__ unsigned short f2bf(float f) {
    unsigned int u = __float_as_uint(f);
    u = (u + 0x7FFFu + ((u >> 16) & 1u)) >> 16;   // RNE
    return (unsigned short)u;
}

struct MegaArgs {
    const float* x; const float* qkv_w; const float* qkv_b;
    const float* proj_w; const float* proj_b; float* out;
    float* qkv; _Float16* Wt_h; float* ctx; _Float16* ctxT; _Float16* vT;
    _Float16* E_A; _Float16* F_A; _Float16* F_B; _Float16* G_A; _Float16* G_B;
    float* rsum; float* rsq; float* csum;
    float* nn; float* scale; float* mu; float* inv_sig; float* negopart;
    float* c2s; _Float16* c2sT; float* gat;
    unsigned int* cnt;
};

// device-scope grid barrier: monotonic counter, target = phase*gridDim
__device__ __forceinline__ void gbar(unsigned int* cnt, unsigned int target) {
    __syncthreads();                      // all waves drained (vmcnt0 before s_barrier)
    if (threadIdx.x == 0) {
        __threadfence();                  // agent fence: wb this XCD's L2
        __hip_atomic_fetch_add(cnt, 1u, __ATOMIC_ACQ_REL, __HIP_MEMORY_SCOPE_AGENT);
        while (__hip_atomic_load(cnt, __ATOMIC_ACQUIRE, __HIP_MEMORY_SCOPE_AGENT) < target)
            __builtin_amdgcn_s_sleep(8);
        __threadfence();                  // inv L1 + L2 (cross-XCD acquire)
    }
    __syncthreads();
}

__device__ __forceinline__ float uload(const float* p) {   // uniform load bypassing scalar K$
    return __hip_atomic_load(p, __ATOMIC_RELAXED, __HIP_MEMORY_SCOPE_AGENT);
}

// ---- mm phase: C[tile] = A @ B^T + bias (fp32 in/out, split bf16x2, 128x128) ----
__device__ void mm_phase(char* smc, const float* A, const float* B, const float* bias,
                         float* C, int K, int ldc, int nx, int vt)
{
    unsigned short (*AsH)[40] = (unsigned short(*)[40])(smc);
    unsigned short (*AsL)[40] = (unsigned short(*)[40])(smc + 10240);
    unsigned short (*BsH)[40] = (unsigned short(*)[40])(smc + 20480);
    unsigned short (*BsL)[40] = (unsigned short(*)[40])(smc + 30720);
    const int row0 = (vt / nx) * 128, col0 = (vt % nx) * 128;
    const int t = threadIdx.x;
    const int wave = t >> 6, lane = t & 63;
    const int ln = lane & 15, quad = lane >> 4;
    const int wm = (wave & 1) * 64, wn = (wave >> 1) * 64;

    f32x4 acc[4][4];
#pragma unroll
    for (int i = 0; i < 4; ++i)
#pragma unroll
        for (int j = 0; j < 4; ++j)
            acc[i][j] = (f32x4){0.f, 0.f, 0.f, 0.f};

    const int sr = t >> 2, sg = (t & 3) * 8;

    for (int k0 = 0; k0 < K; k0 += 32) {
        __syncthreads();
#pragma unroll
        for (int half = 0; half < 4; ++half) {
            const float* src = (half < 2) ? A : B;
            int base = (half < 2) ? row0 : col0;
            int row = sr + ((half & 1) ? 64 : 0);
            const float* p = &src[(long)(base + row) * K + k0 + sg];
            float4 f0 = *(const float4*)p;
            float4 f1 = *(const float4*)(p + 4);
            float fv[8] = {f0.x, f0.y, f0.z, f0.w, f1.x, f1.y, f1.z, f1.w};
            unsigned short hv[8], lv[8];
#pragma unroll
            for (int e = 0; e < 8; ++e) {
                hv[e] = f2bf(fv[e]);
                lv[e] = f2bf(fv[e] - bf2f(hv[e]));
            }
            uint4 H, L;
            H.x = hv[0] | (hv[1] << 16); H.y = hv[2] | (hv[3] << 16);
            H.z = hv[4] | (hv[5] << 16); H.w = hv[6] | (hv[7] << 16);
            L.x = lv[0] | (lv[1] << 16); L.y = lv[2] | (lv[3] << 16);
            L.z = lv[4] | (lv[5] << 16); L.w = lv[6] | (lv[7] << 16);
            if (half < 2) { *(uint4*)&AsH[row][sg] = H; *(uint4*)&AsL[row][sg] = L; }
            else          { *(uint4*)&BsH[row][sg] = H; *(uint4*)&BsL[row][sg] = L; }
        }
        __syncthreads();

        bf16x8s afH[4], afL[4], bfH[4], bfL[4];
#pragma unroll
        for (int mt = 0; mt < 4; ++mt) {
            afH[mt] = *(const bf16x8s*)&AsH[wm + mt * 16 + ln][quad * 8];
            afL[mt] = *(const bf16x8s*)&AsL[wm + mt * 16 + ln][quad * 8];
        }
#pragma unroll
        for (int nt = 0; nt < 4; ++nt) {
            bfH[nt] = *(const bf16x8s*)&BsH[wn + nt * 16 + ln][quad * 8];
            bfL[nt] = *(const bf16x8s*)&BsL[wn + nt * 16 + ln][quad * 8];
        }
#pragma unroll
        for (int mt = 0; mt < 4; ++mt)
#pragma unroll
            for (int nt = 0; nt < 4; ++nt) {
                acc[mt][nt] = __builtin_amdgcn_mfma_f32_16x16x32_bf16(afH[mt], bfH[nt], acc[mt][nt], 0, 0, 0);
                acc[mt][nt] = __builtin_amdgcn_mfma_f32_16x16x32_bf16(afH[mt], bfL[nt], acc[mt][nt], 0, 0, 0);
                acc[mt][nt] = __builtin_amdgcn_mfma_f32_16x16x32_bf16(afL[mt], bfH[nt], acc[mt][nt], 0, 0, 0);
            }
    }

#pragma unroll
    for (int mt = 0; mt < 4; ++mt) {
        const int gr0 = row0 + wm + mt * 16 + quad * 4;
#pragma unroll
        for (int nt = 0; nt < 4; ++nt) {
            const int gc = col0 + wn + nt * 16 + ln;
            float bb = bias[gc];
#pragma unroll
            for (int r = 0; r < 4; ++r)
                C[(long)(gr0 + r) * ldc + gc] = acc[mt][nt][r] + bb;
        }
    }
}

// ---- wt phase: Wt fp16 + row/rowsq/col partials + vT pack (vt in [0,288)) ----
__device__ void wt_phase(char* smc, const MegaArgs& a, int vt)
{
    float (*qs)[128] = (float(*)[128])(smc);
    float (*ks)[128] = (float(*)[128])(smc + 16384);
    float* colacc = (float*)(smc + 32768);
    int z = vt / 18, wx = vt % 18;
    int b = z >> 3, h = z & 7;
    int t = threadIdx.x;
    long zo = (long)z * Ss * Ss;

    if (wx >= 16) {            // vT pack half
        float (*sT)[33] = (float(*)[33])smc;
        int dt = (wx - 16) * 32;
        int d = t & 31, kr = t >> 5;
        for (int kt = 0; kt < Ss; kt += 32) {
            __syncthreads();
#pragma unroll
            for (int p = 0; p < 4; ++p) {
                int kk = kr + p * 8;
                sT[kk][d] = a.qkv[(long)b * (Ss * 3 * DIM) + (long)(kt + kk) * (3 * DIM) + 2 * DIM + h * HD + dt + d];
            }
            __syncthreads();
#pragma unroll
            for (int p = 0; p < 4; ++p) {
                int dd = kr + p * 8;
                a.vT[(long)z * (HD * Ss) + (long)(dt + dd) * Ss + kt + d] = (_Float16)sT[d][dd];
            }
        }
    } else {
        int ti = wx >> 2, tj = wx & 3;
        int i0 = ti * 128, j0 = tj * 128;
        if (tj > ti) {         // fully masked: zero-fill + zero partial slots
            uint4 zz = make_uint4(0, 0, 0, 0);
#pragma unroll
            for (int r = 0; r < 8; ++r) {
                int idx = r * 256 + t;
                int row = idx >> 4, col16 = idx & 15;
                *(uint4*)&a.Wt_h[zo + (long)(j0 + row) * Ss + i0 + col16 * 8] = zz;
            }
            if (t < 128) {
                a.rsum[((z * 4 + ti) * 512) + j0 + t] = 0.f;
                a.rsq [((z * 4 + ti) * 512) + j0 + t] = 0.f;
                a.csum[((z * 4 + tj) * 512) + i0 + t] = 0.f;
            }
        } else {
            int ia = (t & 15) * 4;
            int ja = (t >> 4) * 4;
            const float* qb = a.qkv + (long)b * Ss * (3 * DIM) + h * HD;
            const float* kb = qb + DIM;
            float acc[8][8] = {};

            for (int d0 = 0; d0 < 64; d0 += 32) {
                __syncthreads();
                int col = t & 127, dg = t >> 7;
#pragma unroll
                for (int e = 0; e < 4; ++e) {
                    int d = dg * 16 + e * 4;
                    float4 qv = *(const float4*)&qb[(long)(i0 + col) * (3 * DIM) + d0 + d];
                    float4 kv = *(const float4*)&kb[(long)(j0 + col) * (3 * DIM) + d0 + d];
                    qs[d+0][col] = qv.x; qs[d+1][col] = qv.y; qs[d+2][col] = qv.z; qs[d+3][col] = qv.w;
                    ks[d+0][col] = kv.x; ks[d+1][col] = kv.y; ks[d+2][col] = kv.z; ks[d+3][col] = kv.w;
                }
                __syncthreads();
#pragma unroll
                for (int d = 0; d < 32; ++d) {
                    float4 q0 = *(const float4*)&qs[d][ia];
                    float4 q1 = *(const float4*)&qs[d][ia + 64];
                    float4 k0 = *(const float4*)&ks[d][ja];
                    float4 k1 = *(const float4*)&ks[d][ja + 64];
                    float qv[8] = {q0.x,q0.y,q0.z,q0.w, q1.x,q1.y,q1.z,q1.w};
                    float kv[8] = {k0.x,k0.y,k0.z,k0.w, k1.x,k1.y,k1.z,k1.w};
#pragma unroll
                    for (int aa = 0; aa < 8; ++aa)
#pragma unroll
                        for (int c = 0; c < 8; ++c)
                            acc[aa][c] += fabsf(qv[aa] - kv[c]);
                }
            }

            float cs[8] = {0.f,0.f,0.f,0.f,0.f,0.f,0.f,0.f};
#pragma unroll
            for (int c = 0; c < 8; ++c) {
                int j = j0 + ja + (c & 3) + ((c >> 2) * 64);
                float o[8];
                float rs = 0.f, rq = 0.f;
#pragma unroll
                for (int aa = 0; aa < 8; ++aa) {
                    int i = i0 + ia + (aa & 3) + ((aa >> 2) * 64);
                    float e = expf(-acc[aa][c] * 0.25f);
                    float w = (j <= i) ? e : 0.0f;
                    o[aa] = w;
                    rs += w; rq += w * w; cs[aa] += w;
                }
                _Float16 ha[4] __attribute__((aligned(8))) = {(_Float16)o[0], (_Float16)o[1], (_Float16)o[2], (_Float16)o[3]};
                _Float16 hb[4] __attribute__((aligned(8))) = {(_Float16)o[4], (_Float16)o[5], (_Float16)o[6], (_Float16)o[7]};
                *(uint2*)&a.Wt_h[zo + (long)j * Ss + i0 + ia]      = *(const uint2*)ha;
                *(uint2*)&a.Wt_h[zo + (long)j * Ss + i0 + 64 + ia] = *(const uint2*)hb;
#pragma unroll
                for (int off = 8; off > 0; off >>= 1) {
                    rs += __shfl_down(rs, off, 16);
                    rq += __shfl_down(rq, off, 16);
                }
                if ((t & 15) == 0) {
                    a.rsum[((z * 4 + ti) * 512) + j] = rs;
                    a.rsq [((z * 4 + ti) * 512) + j] = rq;
                }
            }
            __syncthreads();
            if (t < 128) colacc[t] = 0.f;
            __syncthreads();
#pragma unroll
            for (int aa = 0; aa < 8; ++aa)
                atomicAdd(&colacc[ia + (aa & 3) + ((aa >> 2) * 64)], cs[aa]);
            __syncthreads();
            if (t < 128) a.csum[((z * 4 + tj) * 512) + i0 + t] = colacc[t];
        }
    }
}

// ---- NS GEMM phase (fp16, 128x128 tile; tile = blockIdx) ----
__device__ void ns_phase(char* smc, const _Float16* Amat, const _Float16* Bmat,
                         const _Float16* Vmat, _Float16* RA, _Float16* RB,
                         float sign, int tri, int tile)
{
    _Float16 (*As)[40] = (_Float16(*)[40])smc;
    _Float16 (*Bs)[40] = (_Float16(*)[40])(smc + 10240);
    const int z = tile >> 4;
    const long zo = (long)z * Ss * Ss;
    const int row0 = ((tile >> 2) & 3) * 128, col0 = (tile & 3) * 128;
    const int kbeg = (tri == 3) ? row0 : 0;
    const int kend = (tri == 1) ? row0 + 128
                   : (tri == 2) ? ((row0 < col0 ? row0 : col0) + 128) : Ss;
    const int t = threadIdx.x;
    const int wave = t >> 6, lane = t & 63;
    const int ln = lane & 15, quad = lane >> 4;
    const int wm = (wave & 1) * 64, wn = (wave >> 1) * 64;

    f32x4 acc[4][4];
#pragma unroll
    for (int i = 0; i < 4; ++i)
#pragma unroll
        for (int j = 0; j < 4; ++j)
            acc[i][j] = (f32x4){0.f, 0.f, 0.f, 0.f};

    const int r2 = t >> 1, c2 = (t & 1) * 16;

    for (int k0 = kbeg; k0 < kend; k0 += 32) {
        __syncthreads();
        *(uint4*)&As[r2][c2]     = *(const uint4*)&Amat[zo + (long)(row0 + r2) * Ss + k0 + c2];
        *(uint4*)&As[r2][c2 + 8] = *(const uint4*)&Amat[zo + (long)(row0 + r2) * Ss + k0 + c2 + 8];
        *(uint4*)&Bs[r2][c2]     = *(const uint4*)&Bmat[zo + (long)(col0 + r2) * Ss + k0 + c2];
        *(uint4*)&Bs[r2][c2 + 8] = *(const uint4*)&Bmat[zo + (long)(col0 + r2) * Ss + k0 + c2 + 8];
        __syncthreads();

        f16x8 af[4], bf[4];
#pragma unroll
        for (int mt = 0; mt < 4; ++mt)
            af[mt] = *(const f16x8*)&As[wm + mt * 16 + ln][quad * 8];
#pragma unroll
        for (int nt = 0; nt < 4; ++nt)
            bf[nt] = *(const f16x8*)&Bs[wn + nt * 16 + ln][quad * 8];
#pragma unroll
        for (int mt = 0; mt < 4; ++mt)
#pragma unroll
            for (int nt = 0; nt < 4; ++nt)
                acc[mt][nt] = __builtin_amdgcn_mfma_f32_16x16x32_f16(af[mt], bf[nt], acc[mt][nt], 0, 0, 0);
    }

#pragma unroll
    for (int mt = 0; mt < 4; ++mt) {
        const int gr0 = row0 + wm + mt * 16 + quad * 4;
#pragma unroll
        for (int nt = 0; nt < 4; ++nt) {
            const int gc = col0 + wn + nt * 16 + ln;
            _Float16 rb[4] __attribute__((aligned(8)));
#pragma unroll
            for (int r = 0; r < 4; ++r) {
                const long gi = zo + (long)(gr0 + r) * Ss + gc;
                float av = (float)Amat[gi];
                float vv = (float)Vmat[gi];
                _Float16 o = (_Float16)(sign * (av + vv + acc[mt][nt][r]));
                RA[gi] = o;
                rb[r] = o;
            }
            *(uint2*)&RB[zo + (long)gc * Ss + gr0] = *(const uint2*)rb;
        }
    }
}

// ---- skinny GEMM core (64x64 tile x K) ----
__device__ void sk_gemm(char* smc, const _Float16* Ap, const _Float16* Bp,
                        long zA, long zB, int m0, int kbeg, int kend, f32x4* acc)
{
    _Float16 (*As)[40] = (_Float16(*)[40])smc;
    _Float16 (*Bs)[40] = (_Float16(*)[40])(smc + 5120);
    const int t = threadIdx.x;
    const int wave = t >> 6, lane = t & 63;
    const int ln = lane & 15, quad = lane >> 4;
    const int r4 = t >> 2, c4 = (t & 3) * 8;

    for (int k0 = kbeg; k0 < kend; k0 += 32) {
        __syncthreads();
        *(uint4*)&As[r4][c4] = *(const uint4*)&Ap[zA + (long)(m0 + r4) * Ss + k0 + c4];
        *(uint4*)&Bs[r4][c4] = *(const uint4*)&Bp[zB + (long)r4 * Ss + k0 + c4];
        __syncthreads();

        f16x8 af = *(const f16x8*)&As[wave * 16 + ln][quad * 8];
#pragma unroll
        for (int nt = 0; nt < 4; ++nt) {
            f16x8 bf = *(const f16x8*)&Bs[nt * 16 + ln][quad * 8];
            acc[nt] = __builtin_amdgcn_mfma_f32_16x16x32_f16(af, bf, acc[nt], 0, 0, 0);
        }
    }
}

__global__ __launch_bounds__(256) void mega_k(MegaArgs a)
{
    __shared__ __align__(16) char sm[40960];
    const int bx = blockIdx.x;
    const int t = threadIdx.x;
    const long SS = (long)Ss * Ss;
    const long CT = (long)HD * Ss;
    const int wave = t >> 6, lane = t & 63;
    const int ln = lane & 15, quad = lane >> 4;
    unsigned int ph = 0;

    // ---- QKV: qkv = x @ qkv_w^T + qkv_b (96 tiles) ----
    if (bx < 96) mm_phase(sm, a.x, a.qkv_w, a.qkv_b, a.qkv, DIM, 3 * DIM, 12, bx);
    gbar(a.cnt, (++ph) * 256u);

    // ---- WT: Wt fp16 + partials + vT (288 vtiles) ----
    for (int vt = bx; vt < 288; vt += 256) wt_phase(sm, a, vt);
    gbar(a.cnt, (++ph) * 256u);

    // ---- FIN: norms (bx 0..15) + stats (bx 16..23) ----
    if (bx < 16) {
        int z = bx;
        float mx1 = 0.f, mx2 = 0.f;
        for (int jj = t; jj < 512; jj += 256) {
            float rs = 0.f, csv = 0.f;
#pragma unroll
            for (int ti = 0; ti < 4; ++ti) {
                rs  += a.rsum[(z * 4 + ti) * 512 + jj];
                csv += a.csum[(z * 4 + ti) * 512 + jj];
            }
            mx1 = fmaxf(mx1, rs);
            mx2 = fmaxf(mx2, csv);
        }
        float* s1 = (float*)sm;
        float* s2 = s1 + 256;
        s1[t] = mx1; s2[t] = mx2;
        __syncthreads();
        for (int off = 128; off > 0; off >>= 1) {
            if (t < off) {
                s1[t] = fmaxf(s1[t], s1[t + off]);
                s2[t] = fmaxf(s2[t], s2[t + off]);
            }
            __syncthreads();
        }
        if (t == 0) {
            float v = s1[0] * s2[0];
            a.nn[z] = v;
            a.scale[z] = 1.0f / v;
        }
    } else if (bx < 24) {
        int h = bx - 16;
        for (int jj = t; jj < 512; jj += 256) {
            float s = 0.f, q = 0.f;
#pragma unroll
            for (int b = 0; b < 2; ++b)
#pragma unroll
                for (int ti = 0; ti < 4; ++ti) {
                    int zz = b * 8 + h;
                    s += a.rsum[(zz * 4 + ti) * 512 + jj];
                    q += a.rsq [(zz * 4 + ti) * 512 + jj];
                }
            float m_ = s / 1024.f;
            float var = (q - s * s / 1024.f) / 1023.f;
            a.inv_sig[h * 512 + jj] = 1.0f / sqrtf(var + 1e-5f);
            a.mu[h * 512 + jj] = m_;
        }
    }
    gbar(a.cnt, (++ph) * 256u);

    // ---- PREP: E_A, F_A, F_B (4096 vtiles, grid-stride) ----
    {
        float (*tb)[33] = (float(*)[33])sm;
        int c = t & 31, r0 = t >> 5;
        for (int vt = bx; vt < 4096; vt += 256) {
            int z = vt >> 8, ti = (vt >> 4) & 15, tj = vt & 15;
            long zo = (long)z * SS;
            int ti0 = ti * 32, tj0 = tj * 32;
            float s = uload(&a.scale[z]);
#pragma unroll
            for (int p = 0; p < 4; ++p) {
                int r = r0 + p * 8;
                long ia = zo + (long)(ti0 + r) * Ss + tj0 + c;
                float va = (float)a.Wt_h[ia];
                float da = ((ti0 + r) == (tj0 + c)) ? 1.f : 0.f;
                a.F_A[ia] = (_Float16)(va * s - da);
                tb[r][c] = (float)a.Wt_h[zo + (long)(tj0 + r) * Ss + ti0 + c];
            }
            __syncthreads();
#pragma unroll
            for (int p = 0; p < 4; ++p) {
                int r = r0 + p * 8;
                int gi = ti0 + r, gj = tj0 + c;
                float vb = tb[c][r];
                float dd = (gi == gj) ? 1.f : 0.f;
                long oa = zo + (long)gi * Ss + gj;
                a.E_A[oa] = (_Float16)(vb - dd);
                a.F_B[oa] = (_Float16)(vb * s - dd);
            }
            __syncthreads();
        }
    }
    gbar(a.cnt, (++ph) * 256u);

    // ---- SK0: ctx = nn*(F0@v + v) ----
    if (bx < 128) {
        int z = bx >> 3, mb = bx & 7;
        int m0 = mb * 64;
        int b = z >> 3, h = z & 7;
        long zA = (long)z * SS, zB = (long)z * CT;
        float nnz = uload(&a.nn[z]);
        f32x4 acc[4];
#pragma unroll
        for (int i = 0; i < 4; ++i) acc[i] = (f32x4){0.f,0.f,0.f,0.f};
        sk_gemm(sm, a.F_A, a.vT, zA, zB, m0, m0, Ss, acc);
        const int gr = wave * 16 + quad * 4;
#pragma unroll
        for (int nt = 0; nt < 4; ++nt) {
            const int col = nt * 16 + ln;
            _Float16 rb[4] __attribute__((aligned(8)));
#pragma unroll
            for (int r = 0; r < 4; ++r) {
                const int m = m0 + gr + r;
                float vv = a.qkv[(long)b * (Ss * 3 * DIM) + (long)m * (3 * DIM) + 2 * DIM + h * HD + col];
                float val = (vv + acc[nt][r]) * nnz;
                a.ctx[zB + (long)m * HD + col] = val;
                rb[r] = (_Float16)val;
            }
            *(uint2*)&a.ctxT[zB + (long)col * Ss + m0 + gr] = *(const uint2*)rb;
        }
    }
    gbar(a.cnt, (++ph) * 256u);

    // ---- NS x5 ----
    _Float16 *fA = a.F_A, *fB = a.F_B, *gA = a.G_A, *gB = a.G_B;
    for (int it = 0; it < 5; ++it) {
        ns_phase(sm, a.E_A, fB, fA, gA, gB, -1.0f, it == 0 ? 2 : 1, bx);
        gbar(a.cnt, (++ph) * 256u);
        ns_phase(sm, fA, gB, gA, gA, fB, 1.0f, it == 0 ? 3 : 0, bx);
        gbar(a.cnt, (++ph) * 256u);
        _Float16* tmp = fA; fA = gA; gA = tmp;
    }

    // ---- SK1: c2s = inv_sig*(ctx + F@ctx) + negoff partials ----
    if (bx < 128) {
        int z = bx >> 3, mb = bx & 7;
        int m0 = mb * 64;
        int h = z & 7;
        long zA = (long)z * SS, zB = (long)z * CT;
        f32x4 acc[4];
#pragma unroll
        for (int i = 0; i < 4; ++i) acc[i] = (f32x4){0.f,0.f,0.f,0.f};
        sk_gemm(sm, fA, a.ctxT, zA, zB, m0, 0, Ss, acc);
        const int gr = wave * 16 + quad * 4;
        float* red = (float*)(sm + 10240);
        float pcol[4] = {0.f, 0.f, 0.f, 0.f};
#pragma unroll
        for (int nt = 0; nt < 4; ++nt) {
            const int col = nt * 16 + ln;
            _Float16 rb[4] __attribute__((aligned(8)));
#pragma unroll
            for (int r = 0; r < 4; ++r) {
                const int m = m0 + gr + r;
                float vv = a.ctx[zB + (long)m * HD + col];
                float val = a.inv_sig[h * 512 + m] * (vv + acc[nt][r]);
                a.c2s[zB + (long)m * HD + col] = val;
                rb[r] = (_Float16)val;
                pcol[nt] += a.mu[h * 512 + m] * val;
            }
            *(uint2*)&a.c2sT[zB + (long)col * Ss + m0 + gr] = *(const uint2*)rb;
        }
        if (t < 64) red[t] = 0.f;
        __syncthreads();
#pragma unroll
        for (int nt = 0; nt < 4; ++nt)
            atomicAdd(&red[nt * 16 + ln], pcol[nt]);
        __syncthreads();
        if (t < 64)
            a.negopart[(z * 8 + mb) * 64 + t] = red[t];
    }
    gbar(a.cnt, (++ph) * 256u);

    // ---- SK2: gat = c2s + E@c2s - neg ----
    if (bx < 128) {
        int z = bx >> 3, mb = bx & 7;
        int m0 = mb * 64;
        int b = z >> 3, h = z & 7;
        long zA = (long)z * SS, zB = (long)z * CT;
        float* neg = (float*)(sm + 10240);
        if (t < 64) {
            float s = 0.f;
#pragma unroll
            for (int k = 0; k < 8; ++k)
                s += a.negopart[(z * 8 + k) * 64 + t];
            neg[t] = s;
        }
        __syncthreads();
        f32x4 acc[4];
#pragma unroll
        for (int i = 0; i < 4; ++i) acc[i] = (f32x4){0.f,0.f,0.f,0.f};
        sk_gemm(sm, a.E_A, a.c2sT, zA, zB, m0, 0, m0 + 64, acc);
        const int gr = wave * 16 + quad * 4;
#pragma unroll
        for (int nt = 0; nt < 4; ++nt) {
            const int col = nt * 16 + ln;
#pragma unroll
            for (int r = 0; r < 4; ++r) {
                const int m = m0 + gr + r;
                float vv = a.c2s[zB + (long)m * HD + col];
                float val = vv + acc[nt][r] - neg[col];
                a.gat[(long)b * (Ss * DIM) + (long)m * DIM + h * HD + col] = val;
            }
        }
    }
    gbar(a.cnt, (++ph) * 256u);

    // ---- PROJ: out = gat @ proj_w^T + proj_b (32 tiles) ----
    if (bx < 32) mm_phase(sm, a.gat, a.proj_w, a.proj_b, a.out, DIM, DIM, 4, bx);
}

extern "C" void kernel_launch(void* const* d_in, const int* in_sizes, int n_in,
                              void* d_out, int out_size, void* d_ws, size_t ws_size,
                              hipStream_t stream)
{
    float* ws = (float*)d_ws;

    MegaArgs a;
    a.x      = (const float*)d_in[0];
    a.qkv_w  = (const float*)d_in[1];
    a.qkv_b  = (const float*)d_in[2];
    a.proj_w = (const float*)d_in[3];
    a.proj_b = (const float*)d_in[4];
    a.out    = (float*)d_out;

    a.qkv     = ws;                                   // 1,572,864 f
    a.Wt_h    = (_Float16*)(ws + 1572864);            // 4,194,304 h -> f 1572864..3670016
    a.ctx     = ws + 3670016;                         // 524,288 f
    a.ctxT    = (_Float16*)(ws + 4194304);            // f 4194304..4456448
    a.vT      = (_Float16*)(ws + 4456448);            // f 4456448..4718592
    a.E_A     = (_Float16*)(ws + 4718592);            // f ..6815744
    a.F_A     = (_Float16*)(ws + 6815744);            // f ..8912896
    a.F_B     = (_Float16*)(ws + 8912896);            // f ..11010048
    a.G_B     = (_Float16*)(ws + 11010048);           // f ..13107200
    a.rsum    = ws + 13107200;                        // 32768
    a.rsq     = ws + 13139968;                        // 32768
    a.csum    = ws + 13172736;                        // 32768
    a.nn      = ws + 13205504;                        // 16
    a.scale   = ws + 13205520;                        // 16
    a.mu      = ws + 13205536;                        // 4096
    a.inv_sig = ws + 13209632;                        // 4096
    a.negopart= ws + 13213728;                        // 8192
    a.cnt     = (unsigned int*)(ws + 13221920);
    // overlays
    a.G_A  = (_Float16*)(ws + 1572864);               // Wt_h dead after PREP
    a.c2s  = ws;                                      // qkv dead after SK0
    a.c2sT = (_Float16*)(ws + 524288);
    a.gat  = ws + 11010048;                           // G_B dead after NS

    hipMemsetAsync(a.cnt, 0, sizeof(unsigned int), stream);
    mega_k<<<dim3(256), dim3(256), 0, stream>>>(a);
}

// Round 8
// 346.184 us; speedup vs baseline: 3.9630x; 3.9630x over previous
//
#include <hip/hip_runtime.h>

#define Bq 2
#define Hh 8
#define Ss 512
#define HD 64
#define DIM 512

using f32x4   = __attribute__((ext_vector_type(4))) float;
using bf16x8s = __attribute__((ext_vector_type(8))) short;
typedef _Float16 f16x8 __attribute__((ext_vector_type(8)));

__device__ __forceinline__ float bf2f(unsigned short u) {
    return __uint_as_float(((unsigned int)u) << 16);
}
__device__ __forceinline__ unsigned short f2bf(float f) {
    unsigned int u = __float_as_uint(f);
    u = (u + 0x7FFFu + ((u >> 16) & 1u)) >> 16;   // RNE
    return (unsigned short)u;
}

// ============ mm_k: C = A @ B^T + bias (fp32 io, split bf16x2 MFMA, 128x128) ============
__global__ __launch_bounds__(256) void mm_k(
    const float* __restrict__ A, const float* __restrict__ B,
    const float* __restrict__ bias, float* __restrict__ C,
    int K, int ldc)
{
    const int row0 = blockIdx.y * 128, col0 = blockIdx.x * 128;
    __shared__ unsigned short AsH[128][40], AsL[128][40];
    __shared__ unsigned short BsH[128][40], BsL[128][40];
    const int t = threadIdx.x;
    const int wave = t >> 6, lane = t & 63;
    const int ln = lane & 15, quad = lane >> 4;
    const int wm = (wave & 1) * 64, wn = (wave >> 1) * 64;

    f32x4 acc[4][4];
#pragma unroll
    for (int i = 0; i < 4; ++i)
#pragma unroll
        for (int j = 0; j < 4; ++j)
            acc[i][j] = (f32x4){0.f, 0.f, 0.f, 0.f};

    const int sr = t >> 2, sg = (t & 3) * 8;

    for (int k0 = 0; k0 < K; k0 += 32) {
        __syncthreads();
#pragma unroll
        for (int half = 0; half < 4; ++half) {
            const float* src = (half < 2) ? A : B;
            int base = (half < 2) ? row0 : col0;
            int row = sr + ((half & 1) ? 64 : 0);
            const float* p = &src[(long)(base + row) * K + k0 + sg];
            float4 f0 = *(const float4*)p;
            float4 f1 = *(const float4*)(p + 4);
            float fv[8] = {f0.x, f0.y, f0.z, f0.w, f1.x, f1.y, f1.z, f1.w};
            unsigned short hv[8], lv[8];
#pragma unroll
            for (int e = 0; e < 8; ++e) {
                hv[e] = f2bf(fv[e]);
                lv[e] = f2bf(fv[e] - bf2f(hv[e]));
            }
            uint4 H, L;
            H.x = hv[0] | (hv[1] << 16); H.y = hv[2] | (hv[3] << 16);
            H.z = hv[4] | (hv[5] << 16); H.w = hv[6] | (hv[7] << 16);
            L.x = lv[0] | (lv[1] << 16); L.y = lv[2] | (lv[3] << 16);
            L.z = lv[4] | (lv[5] << 16); L.w = lv[6] | (lv[7] << 16);
            if (half < 2) { *(uint4*)&AsH[row][sg] = H; *(uint4*)&AsL[row][sg] = L; }
            else          { *(uint4*)&BsH[row][sg] = H; *(uint4*)&BsL[row][sg] = L; }
        }
        __syncthreads();

        bf16x8s afH[4], afL[4], bfH[4], bfL[4];
#pragma unroll
        for (int mt = 0; mt < 4; ++mt) {
            afH[mt] = *(const bf16x8s*)&AsH[wm + mt * 16 + ln][quad * 8];
            afL[mt] = *(const bf16x8s*)&AsL[wm + mt * 16 + ln][quad * 8];
        }
#pragma unroll
        for (int nt = 0; nt < 4; ++nt) {
            bfH[nt] = *(const bf16x8s*)&BsH[wn + nt * 16 + ln][quad * 8];
            bfL[nt] = *(const bf16x8s*)&BsL[wn + nt * 16 + ln][quad * 8];
        }
#pragma unroll
        for (int mt = 0; mt < 4; ++mt)
#pragma unroll
            for (int nt = 0; nt < 4; ++nt) {
                acc[mt][nt] = __builtin_amdgcn_mfma_f32_16x16x32_bf16(afH[mt], bfH[nt], acc[mt][nt], 0, 0, 0);
                acc[mt][nt] = __builtin_amdgcn_mfma_f32_16x16x32_bf16(afH[mt], bfL[nt], acc[mt][nt], 0, 0, 0);
                acc[mt][nt] = __builtin_amdgcn_mfma_f32_16x16x32_bf16(afL[mt], bfH[nt], acc[mt][nt], 0, 0, 0);
            }
    }

#pragma unroll
    for (int mt = 0; mt < 4; ++mt) {
        const int gr0 = row0 + wm + mt * 16 + quad * 4;
#pragma unroll
        for (int nt = 0; nt < 4; ++nt) {
            const int gc = col0 + wn + nt * 16 + ln;
            float bb = bias[gc];
#pragma unroll
            for (int r = 0; r < 4; ++r)
                C[(long)(gr0 + r) * ldc + gc] = acc[mt][nt][r] + bb;
        }
    }
}

// ============ wt_fused: W fp16 (both layouts) + row/rowsq/col partials + vT ============
__global__ __launch_bounds__(256) void wt_fused(const float* __restrict__ qkv,
                                                _Float16* __restrict__ Wh,
                                                _Float16* __restrict__ Wt,
                                                _Float16* __restrict__ vT,
                                                float* __restrict__ rsum,
                                                float* __restrict__ rsq,
                                                float* __restrict__ csum)
{
    __shared__ float qs[32][128];
    __shared__ float ks[32][128];
    __shared__ float colacc[128];
    int z = blockIdx.y;
    int b = z >> 3, h = z & 7;
    int t = threadIdx.x;
    int bx = blockIdx.x;
    long zo = (long)z * Ss * Ss;

    if (bx >= 16) {            // vT pack: half dh
        float (*sT)[33] = (float(*)[33])qs;
        int dt = (bx - 16) * 32;
        int d = t & 31, kr = t >> 5;
        for (int kt = 0; kt < Ss; kt += 32) {
            __syncthreads();
#pragma unroll
            for (int p = 0; p < 4; ++p) {
                int kk = kr + p * 8;
                sT[kk][d] = qkv[(long)b * (Ss * 3 * DIM) + (long)(kt + kk) * (3 * DIM) + 2 * DIM + h * HD + dt + d];
            }
            __syncthreads();
#pragma unroll
            for (int p = 0; p < 4; ++p) {
                int dd = kr + p * 8;
                vT[(long)z * (HD * Ss) + (long)(dt + dd) * Ss + kt + d] = (_Float16)sT[d][dd];
            }
        }
        return;
    }

    int ti = bx >> 2, tj = bx & 3;
    int i0 = ti * 128, j0 = tj * 128;

    if (tj > ti) {             // fully-masked tile: zero both layouts + partial slots
        uint4 zz = make_uint4(0, 0, 0, 0);
#pragma unroll
        for (int r = 0; r < 8; ++r) {
            int idx = r * 256 + t;
            int row = idx >> 4, col16 = idx & 15;
            *(uint4*)&Wt[zo + (long)(j0 + row) * Ss + i0 + col16 * 8] = zz;
            *(uint4*)&Wh[zo + (long)(i0 + row) * Ss + j0 + col16 * 8] = zz;
        }
        if (t < 128) {
            rsum[((z * 4 + ti) * 512) + j0 + t] = 0.f;
            rsq [((z * 4 + ti) * 512) + j0 + t] = 0.f;
            csum[((z * 4 + tj) * 512) + i0 + t] = 0.f;
        }
        return;
    }

    int ia = (t & 15) * 4;
    int ja = (t >> 4) * 4;
    const float* qb = qkv + (long)b * Ss * (3 * DIM) + h * HD;
    const float* kb = qb + DIM;
    float acc[8][8] = {};

    for (int d0 = 0; d0 < 64; d0 += 32) {
        __syncthreads();
        int col = t & 127, dg = t >> 7;
#pragma unroll
        for (int e = 0; e < 4; ++e) {
            int d = dg * 16 + e * 4;
            float4 qv = *(const float4*)&qb[(long)(i0 + col) * (3 * DIM) + d0 + d];
            float4 kv = *(const float4*)&kb[(long)(j0 + col) * (3 * DIM) + d0 + d];
            qs[d+0][col] = qv.x; qs[d+1][col] = qv.y; qs[d+2][col] = qv.z; qs[d+3][col] = qv.w;
            ks[d+0][col] = kv.x; ks[d+1][col] = kv.y; ks[d+2][col] = kv.z; ks[d+3][col] = kv.w;
        }
        __syncthreads();
#pragma unroll
        for (int d = 0; d < 32; ++d) {
            float4 q0 = *(const float4*)&qs[d][ia];
            float4 q1 = *(const float4*)&qs[d][ia + 64];
            float4 k0 = *(const float4*)&ks[d][ja];
            float4 k1 = *(const float4*)&ks[d][ja + 64];
            float qv[8] = {q0.x,q0.y,q0.z,q0.w, q1.x,q1.y,q1.z,q1.w};
            float kv[8] = {k0.x,k0.y,k0.z,k0.w, k1.x,k1.y,k1.z,k1.w};
#pragma unroll
            for (int aa = 0; aa < 8; ++aa)
#pragma unroll
                for (int c = 0; c < 8; ++c)
                    acc[aa][c] += fabsf(qv[aa] - kv[c]);
        }
    }

    // materialize masked W into acc
#pragma unroll
    for (int aa = 0; aa < 8; ++aa) {
        int i = i0 + ia + (aa & 3) + ((aa >> 2) * 64);
#pragma unroll
        for (int c = 0; c < 8; ++c) {
            int j = j0 + ja + (c & 3) + ((c >> 2) * 64);
            float e = expf(-acc[aa][c] * 0.25f);
            acc[aa][c] = (j <= i) ? e : 0.0f;
        }
    }
    // Wt rows + column-of-W sums (rsum/rsq per j)
#pragma unroll
    for (int c = 0; c < 8; ++c) {
        int j = j0 + ja + (c & 3) + ((c >> 2) * 64);
        float rs = 0.f, rq = 0.f;
#pragma unroll
        for (int aa = 0; aa < 8; ++aa) { rs += acc[aa][c]; rq += acc[aa][c] * acc[aa][c]; }
        _Float16 ha[4] __attribute__((aligned(8))) = {(_Float16)acc[0][c], (_Float16)acc[1][c], (_Float16)acc[2][c], (_Float16)acc[3][c]};
        _Float16 hb[4] __attribute__((aligned(8))) = {(_Float16)acc[4][c], (_Float16)acc[5][c], (_Float16)acc[6][c], (_Float16)acc[7][c]};
        *(uint2*)&Wt[zo + (long)j * Ss + i0 + ia]      = *(const uint2*)ha;
        *(uint2*)&Wt[zo + (long)j * Ss + i0 + 64 + ia] = *(const uint2*)hb;
#pragma unroll
        for (int off = 8; off > 0; off >>= 1) {
            rs += __shfl_down(rs, off, 16);
            rq += __shfl_down(rq, off, 16);
        }
        if ((t & 15) == 0) {
            rsum[((z * 4 + ti) * 512) + j] = rs;
            rsq [((z * 4 + ti) * 512) + j] = rq;
        }
    }
    // Wh rows
#pragma unroll
    for (int aa = 0; aa < 8; ++aa) {
        int i = i0 + ia + (aa & 3) + ((aa >> 2) * 64);
        _Float16 ha[4] __attribute__((aligned(8))) = {(_Float16)acc[aa][0], (_Float16)acc[aa][1], (_Float16)acc[aa][2], (_Float16)acc[aa][3]};
        _Float16 hb[4] __attribute__((aligned(8))) = {(_Float16)acc[aa][4], (_Float16)acc[aa][5], (_Float16)acc[aa][6], (_Float16)acc[aa][7]};
        *(uint2*)&Wh[zo + (long)i * Ss + j0 + ja]      = *(const uint2*)ha;
        *(uint2*)&Wh[zo + (long)i * Ss + j0 + 64 + ja] = *(const uint2*)hb;
    }
    // row-of-W sums (csum per i) via LDS
    __syncthreads();
    if (t < 128) colacc[t] = 0.f;
    __syncthreads();
#pragma unroll
    for (int aa = 0; aa < 8; ++aa) {
        float cs = 0.f;
#pragma unroll
        for (int c = 0; c < 8; ++c) cs += acc[aa][c];
        atomicAdd(&colacc[ia + (aa & 3) + ((aa >> 2) * 64)], cs);
    }
    __syncthreads();
    if (t < 128) csum[((z * 4 + tj) * 512) + i0 + t] = colacc[t];
}

// ============ fin_k: scale[z] = 1/(n1*ninf); mu/inv_sig per (h,j) ============
__global__ __launch_bounds__(256) void fin_k(const float* __restrict__ rsum,
                                             const float* __restrict__ rsq,
                                             const float* __restrict__ csum,
                                             float* __restrict__ scal,
                                             float* __restrict__ mu,
                                             float* __restrict__ inv_sig)
{
    __shared__ float s1[256], s2[256];
    int bx = blockIdx.x, t = threadIdx.x;
    if (bx < 16) {
        int z = bx;
        float mx1 = 0.f, mx2 = 0.f;
        for (int jj = t; jj < 512; jj += 256) {
            float rs = 0.f, cs = 0.f;
#pragma unroll
            for (int ti = 0; ti < 4; ++ti) {
                rs += rsum[(z * 4 + ti) * 512 + jj];
                cs += csum[(z * 4 + ti) * 512 + jj];
            }
            mx1 = fmaxf(mx1, rs);    // n1 = max colsum(W)
            mx2 = fmaxf(mx2, cs);    // ninf = max rowsum(W)
        }
        s1[t] = mx1; s2[t] = mx2;
        __syncthreads();
        for (int off = 128; off > 0; off >>= 1) {
            if (t < off) {
                s1[t] = fmaxf(s1[t], s1[t + off]);
                s2[t] = fmaxf(s2[t], s2[t + off]);
            }
            __syncthreads();
        }
        if (t == 0) scal[z] = 1.0f / (s1[0] * s2[0]);
    } else {
        int h = bx - 16;
        for (int jj = t; jj < 512; jj += 256) {
            float s = 0.f, q = 0.f;
#pragma unroll
            for (int b = 0; b < 2; ++b)
#pragma unroll
                for (int ti = 0; ti < 4; ++ti) {
                    int zz = b * 8 + h;
                    s += rsum[(zz * 4 + ti) * 512 + jj];
                    q += rsq [(zz * 4 + ti) * 512 + jj];
                }
            float m_ = s / 1024.f;
            float var = (q - s * s / 1024.f) / 1023.f;
            inv_sig[h * 512 + jj] = 1.0f / sqrtf(var + 1e-5f);
            mu[h * 512 + jj] = m_;
        }
    }
}

// ============ fg_k<MODE>: full 512x512 fp16 GEMM, C[m][n] = sum_k A[m][k]B[n][k] ============
// MODE 0: T0 = -s * Wh@Wh^T (tri: kend=min+128).  MODE 1: T' = 2*V|_C + A@A (full K).
template<int MODE>
__global__ __launch_bounds__(256) void fg_k(const _Float16* __restrict__ A,
                                            const _Float16* __restrict__ B,
                                            const _Float16* V,
                                            _Float16* __restrict__ R,
                                            const float* __restrict__ scal)
{
    __shared__ _Float16 As[128][40];
    __shared__ _Float16 Bs[128][40];
    const int z = blockIdx.y;
    const long zo = (long)z * Ss * Ss;
    const int tile = blockIdx.x;
    const int row0 = (tile >> 2) * 128, col0 = (tile & 3) * 128;
    const int kend = (MODE == 0) ? ((row0 < col0 ? row0 : col0) + 128) : Ss;
    const int t = threadIdx.x;
    const int wave = t >> 6, lane = t & 63;
    const int ln = lane & 15, quad = lane >> 4;
    const int wm = (wave & 1) * 64, wn = (wave >> 1) * 64;

    f32x4 acc[4][4];
#pragma unroll
    for (int i = 0; i < 4; ++i)
#pragma unroll
        for (int j = 0; j < 4; ++j)
            acc[i][j] = (f32x4){0.f, 0.f, 0.f, 0.f};

    const int r2 = t >> 1, c2 = (t & 1) * 16;

    for (int k0 = 0; k0 < kend; k0 += 32) {
        __syncthreads();
        *(uint4*)&As[r2][c2]     = *(const uint4*)&A[zo + (long)(row0 + r2) * Ss + k0 + c2];
        *(uint4*)&As[r2][c2 + 8] = *(const uint4*)&A[zo + (long)(row0 + r2) * Ss + k0 + c2 + 8];
        *(uint4*)&Bs[r2][c2]     = *(const uint4*)&B[zo + (long)(col0 + r2) * Ss + k0 + c2];
        *(uint4*)&Bs[r2][c2 + 8] = *(const uint4*)&B[zo + (long)(col0 + r2) * Ss + k0 + c2 + 8];
        __syncthreads();

        f16x8 af[4], bf[4];
#pragma unroll
        for (int mt = 0; mt < 4; ++mt)
            af[mt] = *(const f16x8*)&As[wm + mt * 16 + ln][quad * 8];
#pragma unroll
        for (int nt = 0; nt < 4; ++nt)
            bf[nt] = *(const f16x8*)&Bs[wn + nt * 16 + ln][quad * 8];
#pragma unroll
        for (int mt = 0; mt < 4; ++mt)
#pragma unroll
            for (int nt = 0; nt < 4; ++nt)
                acc[mt][nt] = __builtin_amdgcn_mfma_f32_16x16x32_f16(af[mt], bf[nt], acc[mt][nt], 0, 0, 0);
    }

    float s = (MODE == 0) ? scal[z] : 0.f;
#pragma unroll
    for (int mt = 0; mt < 4; ++mt) {
        const int gr0 = row0 + wm + mt * 16 + quad * 4;
#pragma unroll
        for (int nt = 0; nt < 4; ++nt) {
            const int gc = col0 + wn + nt * 16 + ln;
#pragma unroll
            for (int r = 0; r < 4; ++r) {
                const long gi = zo + (long)(gr0 + r) * Ss + gc;
                float val;
                if (MODE == 0) val = -s * acc[mt][nt][r];
                else           val = 2.0f * (float)V[gi] + acc[mt][nt][r];
                R[gi] = (_Float16)val;
            }
        }
    }
}

// ============ wk_k<MODE>: wide 64x512 fp16 GEMM, C[d][n] = sum_k A[d][k]B[n][k] ============
// MODE 0: ctxT = vT x Wt (kbeg=col0). MODE 1: Y' = 2*V|_C + Y x T (full K).
// MODE 2: c2sT = inv_sig[n] * s * (Y x Wt) (kbeg=col0) + negoff partials.
template<int MODE>
__global__ __launch_bounds__(256) void wk_k(const _Float16* __restrict__ A,
                                            const _Float16* __restrict__ B,
                                            const _Float16* V,
                                            _Float16* __restrict__ R,
                                            const float* __restrict__ scal,
                                            const float* __restrict__ inv_sig,
                                            const float* __restrict__ mu,
                                            float* __restrict__ negopart)
{
    __shared__ _Float16 As[64][40];
    __shared__ _Float16 Bs[64][40];
    __shared__ float red[64];
    const int z = blockIdx.y;
    const int h = z & 7;
    const int col0 = blockIdx.x * 64;
    const long zA = (long)z * (HD * Ss);
    const long zB = (long)z * Ss * Ss;
    const int kbeg = (MODE == 1) ? 0 : col0;
    const int t = threadIdx.x;
    const int wave = t >> 6, lane = t & 63;
    const int ln = lane & 15, quad = lane >> 4;
    const int r4 = t >> 2, c4 = (t & 3) * 8;

    f32x4 acc[4];
#pragma unroll
    for (int i = 0; i < 4; ++i) acc[i] = (f32x4){0.f, 0.f, 0.f, 0.f};

    for (int k0 = kbeg; k0 < Ss; k0 += 32) {
        __syncthreads();
        *(uint4*)&As[r4][c4] = *(const uint4*)&A[zA + (long)r4 * Ss + k0 + c4];
        *(uint4*)&Bs[r4][c4] = *(const uint4*)&B[zB + (long)(col0 + r4) * Ss + k0 + c4];
        __syncthreads();

        f16x8 af = *(const f16x8*)&As[wave * 16 + ln][quad * 8];
#pragma unroll
        for (int nt = 0; nt < 4; ++nt) {
            f16x8 bf = *(const f16x8*)&Bs[nt * 16 + ln][quad * 8];
            acc[nt] = __builtin_amdgcn_mfma_f32_16x16x32_f16(af, bf, acc[nt], 0, 0, 0);
        }
    }

    if (MODE == 2) {
        if (t < 64) red[t] = 0.f;
        __syncthreads();
    }
    const int gr = wave * 16 + quad * 4;
    float pr[4] = {0.f, 0.f, 0.f, 0.f};
    float s = (MODE == 2) ? scal[z] : 0.f;
#pragma unroll
    for (int nt = 0; nt < 4; ++nt) {
        const int gc = col0 + nt * 16 + ln;
#pragma unroll
        for (int r = 0; r < 4; ++r) {
            const int d = gr + r;
            float val;
            if (MODE == 0)      val = acc[nt][r];
            else if (MODE == 1) val = 2.0f * (float)V[zA + (long)d * Ss + gc] + acc[nt][r];
            else {
                val = inv_sig[h * 512 + gc] * (s * acc[nt][r]);
                pr[r] += mu[h * 512 + gc] * val;
            }
            R[zA + (long)d * Ss + gc] = (_Float16)val;
        }
    }
    if (MODE == 2) {
#pragma unroll
        for (int r = 0; r < 4; ++r)
            atomicAdd(&red[gr + r], pr[r]);
        __syncthreads();
        if (t < 64)
            negopart[(z * 8 + blockIdx.x) * 64 + t] = red[t];
    }
}

// ============ ga_k: gat = Wh @ c2s - neg, fp32 out in [B,S,DIM] layout ============
__global__ __launch_bounds__(256) void ga_k(const _Float16* __restrict__ Wh,
                                            const _Float16* __restrict__ c2sT,
                                            const float* __restrict__ negopart,
                                            float* __restrict__ gat)
{
    __shared__ _Float16 As[64][40];
    __shared__ _Float16 Bs[64][40];
    __shared__ float neg[64];
    const int z = blockIdx.y;
    const int b = z >> 3, h = z & 7;
    const int m0 = blockIdx.x * 64;
    const long zA = (long)z * Ss * Ss;
    const long zB = (long)z * (HD * Ss);
    const int t = threadIdx.x;
    const int wave = t >> 6, lane = t & 63;
    const int ln = lane & 15, quad = lane >> 4;
    const int r4 = t >> 2, c4 = (t & 3) * 8;

    if (t < 64) {
        float s = 0.f;
#pragma unroll
        for (int k = 0; k < 8; ++k) s += negopart[(z * 8 + k) * 64 + t];
        neg[t] = s;
    }
    __syncthreads();

    f32x4 acc[4];
#pragma unroll
    for (int i = 0; i < 4; ++i) acc[i] = (f32x4){0.f, 0.f, 0.f, 0.f};

    for (int k0 = 0; k0 < m0 + 64; k0 += 32) {   // W row m has k <= m
        __syncthreads();
        *(uint4*)&As[r4][c4] = *(const uint4*)&Wh[zA + (long)(m0 + r4) * Ss + k0 + c4];
        *(uint4*)&Bs[r4][c4] = *(const uint4*)&c2sT[zB + (long)r4 * Ss + k0 + c4];
        __syncthreads();

        f16x8 af = *(const f16x8*)&As[wave * 16 + ln][quad * 8];
#pragma unroll
        for (int nt = 0; nt < 4; ++nt) {
            f16x8 bf = *(const f16x8*)&Bs[nt * 16 + ln][quad * 8];
            acc[nt] = __builtin_amdgcn_mfma_f32_16x16x32_f16(af, bf, acc[nt], 0, 0, 0);
        }
    }

    const int gr = wave * 16 + quad * 4;
#pragma unroll
    for (int nt = 0; nt < 4; ++nt) {
        const int col = nt * 16 + ln;
#pragma unroll
        for (int r = 0; r < 4; ++r) {
            const int m = m0 + gr + r;
            gat[(long)b * (Ss * DIM) + (long)m * DIM + h * HD + col] = acc[nt][r] - neg[col];
        }
    }
}

extern "C" void kernel_launch(void* const* d_in, const int* in_sizes, int n_in,
                              void* d_out, int out_size, void* d_ws, size_t ws_size,
                              hipStream_t stream)
{
    const float* x      = (const float*)d_in[0];
    const float* qkv_w  = (const float*)d_in[1];
    const float* qkv_b  = (const float*)d_in[2];
    const float* proj_w = (const float*)d_in[3];
    const float* proj_b = (const float*)d_in[4];
    float* out = (float*)d_out;
    float* ws  = (float*)d_ws;

    float* qkv     = ws;                                   // 1,572,864 f
    _Float16* Wh   = (_Float16*)(ws + 1572864);            // 2,097,152 f
    _Float16* Wt   = (_Float16*)(ws + 3670016);            // 2,097,152 f
    _Float16* vT   = (_Float16*)(ws + 5767168);            //   262,144 f
    _Float16* T[5];
    for (int i = 0; i < 5; ++i) T[i] = (_Float16*)(ws + 6029312 + (long)i * 2097152);
    _Float16* Ya   = (_Float16*)(ws + 16515072);           //   262,144 f
    _Float16* Yb   = (_Float16*)(ws + 16777216);
    _Float16* c2sT = (_Float16*)(ws + 17039360);
    float* rsum    = ws + 17301504;                        // 32768
    float* rsq     = ws + 17334272;
    float* csum    = ws + 17367040;
    float* scal    = ws + 17399808;                        // 16
    float* mu      = ws + 17399824;                        // 4096
    float* inv_sig = ws + 17403920;                        // 4096
    float* negp    = ws + 17408016;                        // 8192
    float* gat     = ws + 17416208;                        // 524288 -> end 17,940,496 f (~72 MB)

    dim3 blk(256);

    // 1. qkv = x @ qkv_w^T + qkv_b
    mm_k<<<dim3(12, 8), blk, 0, stream>>>(x, qkv_w, qkv_b, qkv, DIM, 3 * DIM);

    // 2. W fp16 (both layouts) + reduction partials + vT
    wt_fused<<<dim3(18, 16), blk, 0, stream>>>(qkv, Wh, Wt, vT, rsum, rsq, csum);

    // 3. scale + whitening stats
    fin_k<<<dim3(24), blk, 0, stream>>>(rsum, rsq, csum, scal, mu, inv_sig);

    // 4. T0 = -s * W W^T  (symmetric)
    fg_k<0><<<dim3(16, 16), blk, 0, stream>>>(Wh, Wh, nullptr, T[0], scal);

    // 5-8. residual squarings: T_{k+1} = 2*T_k + T_k^2  (symmetry preserved)
    for (int i = 0; i < 4; ++i)
        fg_k<1><<<dim3(16, 16), blk, 0, stream>>>(T[i], T[i], T[i], T[i + 1], nullptr);

    // 9. ctxT = (W^T v)^T  = vT x Wt
    wk_k<0><<<dim3(8, 16), blk, 0, stream>>>(vT, Wt, nullptr, Ya, nullptr, nullptr, nullptr, nullptr);

    // 10-14. y^T <- 2 y^T + y^T T_k, k = 4..0   (X5 = s W^T (2I+T0)...(2I+T4))
    _Float16* yc = Ya;
    _Float16* yn = Yb;
    for (int k = 4; k >= 0; --k) {
        wk_k<1><<<dim3(8, 16), blk, 0, stream>>>(yc, T[k], yc, yn, nullptr, nullptr, nullptr, nullptr);
        _Float16* tmp = yc; yc = yn; yn = tmp;
    }

    // 15. c2sT = inv_sig * s * (y^T W) + negoff partials
    wk_k<2><<<dim3(8, 16), blk, 0, stream>>>(yc, Wt, nullptr, c2sT, scal, inv_sig, mu, negp);

    // 16. gat = W @ c2s - neg  (tri kend)
    ga_k<<<dim3(8, 16), blk, 0, stream>>>(Wh, c2sT, negp, gat);

    // 17. out = gat @ proj_w^T + proj_b
    mm_k<<<dim3(4, 8), blk, 0, stream>>>(gat, proj_w, proj_b, out, DIM, DIM);
}

// Round 9
// 328.278 us; speedup vs baseline: 4.1791x; 1.0545x over previous
//
#include <hip/hip_runtime.h>

#define Bq 2
#define Hh 8
#define Ss 512
#define HD 64
#define DIM 512

using f32x4   = __attribute__((ext_vector_type(4))) float;
using bf16x8s = __attribute__((ext_vector_type(8))) short;
typedef _Float16 f16x8 __attribute__((ext_vector_type(8)));

__device__ __forceinline__ float bf2f(unsigned short u) {
    return __uint_as_float(((unsigned int)u) << 16);
}
__device__ __forceinline__ unsigned short f2bf(float f) {
    unsigned int u = __float_as_uint(f);
    u = (u + 0x7FFFu + ((u >> 16) & 1u)) >> 16;   // RNE
    return (unsigned short)u;
}

// ============ mm_k: C = A @ B^T + bias (fp32 io, split bf16x2 MFMA, 128x128) ============
__global__ __launch_bounds__(256) void mm_k(
    const float* __restrict__ A, const float* __restrict__ B,
    const float* __restrict__ bias, float* __restrict__ C,
    int K, int ldc)
{
    const int row0 = blockIdx.y * 128, col0 = blockIdx.x * 128;
    __shared__ unsigned short AsH[128][40], AsL[128][40];
    __shared__ unsigned short BsH[128][40], BsL[128][40];
    const int t = threadIdx.x;
    const int wave = t >> 6, lane = t & 63;
    const int ln = lane & 15, quad = lane >> 4;
    const int wm = (wave & 1) * 64, wn = (wave >> 1) * 64;

    f32x4 acc[4][4];
#pragma unroll
    for (int i = 0; i < 4; ++i)
#pragma unroll
        for (int j = 0; j < 4; ++j)
            acc[i][j] = (f32x4){0.f, 0.f, 0.f, 0.f};

    const int sr = t >> 2, sg = (t & 3) * 8;

    for (int k0 = 0; k0 < K; k0 += 32) {
        __syncthreads();
#pragma unroll
        for (int half = 0; half < 4; ++half) {
            const float* src = (half < 2) ? A : B;
            int base = (half < 2) ? row0 : col0;
            int row = sr + ((half & 1) ? 64 : 0);
            const float* p = &src[(long)(base + row) * K + k0 + sg];
            float4 f0 = *(const float4*)p;
            float4 f1 = *(const float4*)(p + 4);
            float fv[8] = {f0.x, f0.y, f0.z, f0.w, f1.x, f1.y, f1.z, f1.w};
            unsigned short hv[8], lv[8];
#pragma unroll
            for (int e = 0; e < 8; ++e) {
                hv[e] = f2bf(fv[e]);
                lv[e] = f2bf(fv[e] - bf2f(hv[e]));
            }
            uint4 H, L;
            H.x = hv[0] | (hv[1] << 16); H.y = hv[2] | (hv[3] << 16);
            H.z = hv[4] | (hv[5] << 16); H.w = hv[6] | (hv[7] << 16);
            L.x = lv[0] | (lv[1] << 16); L.y = lv[2] | (lv[3] << 16);
            L.z = lv[4] | (lv[5] << 16); L.w = lv[6] | (lv[7] << 16);
            if (half < 2) { *(uint4*)&AsH[row][sg] = H; *(uint4*)&AsL[row][sg] = L; }
            else          { *(uint4*)&BsH[row][sg] = H; *(uint4*)&BsL[row][sg] = L; }
        }
        __syncthreads();

        bf16x8s afH[4], afL[4], bfH[4], bfL[4];
#pragma unroll
        for (int mt = 0; mt < 4; ++mt) {
            afH[mt] = *(const bf16x8s*)&AsH[wm + mt * 16 + ln][quad * 8];
            afL[mt] = *(const bf16x8s*)&AsL[wm + mt * 16 + ln][quad * 8];
        }
#pragma unroll
        for (int nt = 0; nt < 4; ++nt) {
            bfH[nt] = *(const bf16x8s*)&BsH[wn + nt * 16 + ln][quad * 8];
            bfL[nt] = *(const bf16x8s*)&BsL[wn + nt * 16 + ln][quad * 8];
        }
#pragma unroll
        for (int mt = 0; mt < 4; ++mt)
#pragma unroll
            for (int nt = 0; nt < 4; ++nt) {
                acc[mt][nt] = __builtin_amdgcn_mfma_f32_16x16x32_bf16(afH[mt], bfH[nt], acc[mt][nt], 0, 0, 0);
                acc[mt][nt] = __builtin_amdgcn_mfma_f32_16x16x32_bf16(afH[mt], bfL[nt], acc[mt][nt], 0, 0, 0);
                acc[mt][nt] = __builtin_amdgcn_mfma_f32_16x16x32_bf16(afL[mt], bfH[nt], acc[mt][nt], 0, 0, 0);
            }
    }

#pragma unroll
    for (int mt = 0; mt < 4; ++mt) {
        const int gr0 = row0 + wm + mt * 16 + quad * 4;
#pragma unroll
        for (int nt = 0; nt < 4; ++nt) {
            const int gc = col0 + wn + nt * 16 + ln;
            float bb = bias[gc];
#pragma unroll
            for (int r = 0; r < 4; ++r)
                C[(long)(gr0 + r) * ldc + gc] = acc[mt][nt][r] + bb;
        }
    }
}

// ============ wt_fused: W fp16 (both layouts) + row/rowsq/col partials + vT ============
__global__ __launch_bounds__(256) void wt_fused(const float* __restrict__ qkv,
                                                _Float16* __restrict__ Wh,
                                                _Float16* __restrict__ Wt,
                                                _Float16* __restrict__ vT,
                                                float* __restrict__ rsum,
                                                float* __restrict__ rsq,
                                                float* __restrict__ csum)
{
    __shared__ float qs[32][128];
    __shared__ float ks[32][128];
    __shared__ float colacc[128];
    int z = blockIdx.y;
    int b = z >> 3, h = z & 7;
    int t = threadIdx.x;
    int bx = blockIdx.x;
    long zo = (long)z * Ss * Ss;

    if (bx >= 16) {            // vT pack: half dh
        float (*sT)[33] = (float(*)[33])qs;
        int dt = (bx - 16) * 32;
        int d = t & 31, kr = t >> 5;
        for (int kt = 0; kt < Ss; kt += 32) {
            __syncthreads();
#pragma unroll
            for (int p = 0; p < 4; ++p) {
                int kk = kr + p * 8;
                sT[kk][d] = qkv[(long)b * (Ss * 3 * DIM) + (long)(kt + kk) * (3 * DIM) + 2 * DIM + h * HD + dt + d];
            }
            __syncthreads();
#pragma unroll
            for (int p = 0; p < 4; ++p) {
                int dd = kr + p * 8;
                vT[(long)z * (HD * Ss) + (long)(dt + dd) * Ss + kt + d] = (_Float16)sT[d][dd];
            }
        }
        return;
    }

    int ti = bx >> 2, tj = bx & 3;
    int i0 = ti * 128, j0 = tj * 128;

    if (tj > ti) {             // fully-masked tile: zero both layouts + partial slots
        uint4 zz = make_uint4(0, 0, 0, 0);
#pragma unroll
        for (int r = 0; r < 8; ++r) {
            int idx = r * 256 + t;
            int row = idx >> 4, col16 = idx & 15;
            *(uint4*)&Wt[zo + (long)(j0 + row) * Ss + i0 + col16 * 8] = zz;
            *(uint4*)&Wh[zo + (long)(i0 + row) * Ss + j0 + col16 * 8] = zz;
        }
        if (t < 128) {
            rsum[((z * 4 + ti) * 512) + j0 + t] = 0.f;
            rsq [((z * 4 + ti) * 512) + j0 + t] = 0.f;
            csum[((z * 4 + tj) * 512) + i0 + t] = 0.f;
        }
        return;
    }

    int ia = (t & 15) * 4;
    int ja = (t >> 4) * 4;
    const float* qb = qkv + (long)b * Ss * (3 * DIM) + h * HD;
    const float* kb = qb + DIM;
    float acc[8][8] = {};

    for (int d0 = 0; d0 < 64; d0 += 32) {
        __syncthreads();
        int col = t & 127, dg = t >> 7;
#pragma unroll
        for (int e = 0; e < 4; ++e) {
            int d = dg * 16 + e * 4;
            float4 qv = *(const float4*)&qb[(long)(i0 + col) * (3 * DIM) + d0 + d];
            float4 kv = *(const float4*)&kb[(long)(j0 + col) * (3 * DIM) + d0 + d];
            qs[d+0][col] = qv.x; qs[d+1][col] = qv.y; qs[d+2][col] = qv.z; qs[d+3][col] = qv.w;
            ks[d+0][col] = kv.x; ks[d+1][col] = kv.y; ks[d+2][col] = kv.z; ks[d+3][col] = kv.w;
        }
        __syncthreads();
#pragma unroll
        for (int d = 0; d < 32; ++d) {
            float4 q0 = *(const float4*)&qs[d][ia];
            float4 q1 = *(const float4*)&qs[d][ia + 64];
            float4 k0 = *(const float4*)&ks[d][ja];
            float4 k1 = *(const float4*)&ks[d][ja + 64];
            float qv[8] = {q0.x,q0.y,q0.z,q0.w, q1.x,q1.y,q1.z,q1.w};
            float kv[8] = {k0.x,k0.y,k0.z,k0.w, k1.x,k1.y,k1.z,k1.w};
#pragma unroll
            for (int aa = 0; aa < 8; ++aa)
#pragma unroll
                for (int c = 0; c < 8; ++c)
                    acc[aa][c] += fabsf(qv[aa] - kv[c]);
        }
    }

#pragma unroll
    for (int aa = 0; aa < 8; ++aa) {
        int i = i0 + ia + (aa & 3) + ((aa >> 2) * 64);
#pragma unroll
        for (int c = 0; c < 8; ++c) {
            int j = j0 + ja + (c & 3) + ((c >> 2) * 64);
            float e = expf(-acc[aa][c] * 0.25f);
            acc[aa][c] = (j <= i) ? e : 0.0f;
        }
    }
#pragma unroll
    for (int c = 0; c < 8; ++c) {
        int j = j0 + ja + (c & 3) + ((c >> 2) * 64);
        float rs = 0.f, rq = 0.f;
#pragma unroll
        for (int aa = 0; aa < 8; ++aa) { rs += acc[aa][c]; rq += acc[aa][c] * acc[aa][c]; }
        _Float16 ha[4] __attribute__((aligned(8))) = {(_Float16)acc[0][c], (_Float16)acc[1][c], (_Float16)acc[2][c], (_Float16)acc[3][c]};
        _Float16 hb[4] __attribute__((aligned(8))) = {(_Float16)acc[4][c], (_Float16)acc[5][c], (_Float16)acc[6][c], (_Float16)acc[7][c]};
        *(uint2*)&Wt[zo + (long)j * Ss + i0 + ia]      = *(const uint2*)ha;
        *(uint2*)&Wt[zo + (long)j * Ss + i0 + 64 + ia] = *(const uint2*)hb;
#pragma unroll
        for (int off = 8; off > 0; off >>= 1) {
            rs += __shfl_down(rs, off, 16);
            rq += __shfl_down(rq, off, 16);
        }
        if ((t & 15) == 0) {
            rsum[((z * 4 + ti) * 512) + j] = rs;
            rsq [((z * 4 + ti) * 512) + j] = rq;
        }
    }
#pragma unroll
    for (int aa = 0; aa < 8; ++aa) {
        int i = i0 + ia + (aa & 3) + ((aa >> 2) * 64);
        _Float16 ha[4] __attribute__((aligned(8))) = {(_Float16)acc[aa][0], (_Float16)acc[aa][1], (_Float16)acc[aa][2], (_Float16)acc[aa][3]};
        _Float16 hb[4] __attribute__((aligned(8))) = {(_Float16)acc[aa][4], (_Float16)acc[aa][5], (_Float16)acc[aa][6], (_Float16)acc[aa][7]};
        *(uint2*)&Wh[zo + (long)i * Ss + j0 + ja]      = *(const uint2*)ha;
        *(uint2*)&Wh[zo + (long)i * Ss + j0 + 64 + ja] = *(const uint2*)hb;
    }
    __syncthreads();
    if (t < 128) colacc[t] = 0.f;
    __syncthreads();
#pragma unroll
    for (int aa = 0; aa < 8; ++aa) {
        float cs = 0.f;
#pragma unroll
        for (int c = 0; c < 8; ++c) cs += acc[aa][c];
        atomicAdd(&colacc[ia + (aa & 3) + ((aa >> 2) * 64)], cs);
    }
    __syncthreads();
    if (t < 128) csum[((z * 4 + tj) * 512) + i0 + t] = colacc[t];
}

// ============ wk GEMM device core (pipelined): acc += A[64xK] x B[64-chunk of 512 x K] ============
__device__ __forceinline__ void wk_core(char* smc, const _Float16* A, const _Float16* B,
                                        long zA, long zB, int col0, int kbeg, int kend,
                                        f32x4* acc)
{
    _Float16 (*As)[40] = (_Float16(*)[40])smc;
    _Float16 (*Bs)[40] = (_Float16(*)[40])(smc + 5120);
    const int t = threadIdx.x;
    const int wave = t >> 6, lane = t & 63;
    const int ln = lane & 15, quad = lane >> 4;
    const int r4 = t >> 2, c4 = (t & 3) * 8;
    const long aoff = zA + (long)r4 * Ss;
    const long boff = zB + (long)(col0 + r4) * Ss;

    uint4 ua = *(const uint4*)&A[aoff + kbeg + c4];
    uint4 ub = *(const uint4*)&B[boff + kbeg + c4];
    for (int k0 = kbeg; k0 < kend; k0 += 32) {
        *(uint4*)&As[r4][c4] = ua;
        *(uint4*)&Bs[r4][c4] = ub;
        __syncthreads();
        int kn = k0 + 32;
        if (kn < kend) {
            ua = *(const uint4*)&A[aoff + kn + c4];
            ub = *(const uint4*)&B[boff + kn + c4];
        }
        f16x8 af = *(const f16x8*)&As[wave * 16 + ln][quad * 8];
#pragma unroll
        for (int nt = 0; nt < 4; ++nt) {
            f16x8 bf = *(const f16x8*)&Bs[nt * 16 + ln][quad * 8];
            acc[nt] = __builtin_amdgcn_mfma_f32_16x16x32_f16(af, bf, acc[nt], 0, 0, 0);
        }
        __syncthreads();
    }
}

// ============ mid_k: blocks 0..127 -> ctxT = vT x Wt; blocks 128..151 -> fin ============
__global__ __launch_bounds__(256) void mid_k(const _Float16* __restrict__ vT,
                                             const _Float16* __restrict__ Wt,
                                             _Float16* __restrict__ ctxT,
                                             const float* __restrict__ rsum,
                                             const float* __restrict__ rsq,
                                             const float* __restrict__ csum,
                                             float* __restrict__ scal,
                                             float* __restrict__ mu,
                                             float* __restrict__ inv_sig)
{
    __shared__ __align__(16) char sm[10240];
    int bx = blockIdx.x, t = threadIdx.x;
    if (bx < 128) {
        int z = bx >> 3, cc = bx & 7;
        int col0 = cc * 64;
        long zA = (long)z * (HD * Ss), zB = (long)z * Ss * Ss;
        f32x4 acc[4];
#pragma unroll
        for (int i = 0; i < 4; ++i) acc[i] = (f32x4){0.f, 0.f, 0.f, 0.f};
        wk_core(sm, vT, Wt, zA, zB, col0, col0, Ss, acc);
        const int wave = t >> 6, lane = t & 63;
        const int ln = lane & 15, quad = lane >> 4;
        const int gr = wave * 16 + quad * 4;
#pragma unroll
        for (int nt = 0; nt < 4; ++nt) {
            const int gc = col0 + nt * 16 + ln;
#pragma unroll
            for (int r = 0; r < 4; ++r)
                ctxT[zA + (long)(gr + r) * Ss + gc] = (_Float16)acc[nt][r];
        }
    } else if (bx < 144) {
        int z = bx - 128;
        float* s1 = (float*)sm;
        float* s2 = s1 + 256;
        float mx1 = 0.f, mx2 = 0.f;
        for (int jj = t; jj < 512; jj += 256) {
            float rs = 0.f, cs = 0.f;
#pragma unroll
            for (int ti = 0; ti < 4; ++ti) {
                rs += rsum[(z * 4 + ti) * 512 + jj];
                cs += csum[(z * 4 + ti) * 512 + jj];
            }
            mx1 = fmaxf(mx1, rs);
            mx2 = fmaxf(mx2, cs);
        }
        s1[t] = mx1; s2[t] = mx2;
        __syncthreads();
        for (int off = 128; off > 0; off >>= 1) {
            if (t < off) {
                s1[t] = fmaxf(s1[t], s1[t + off]);
                s2[t] = fmaxf(s2[t], s2[t + off]);
            }
            __syncthreads();
        }
        if (t == 0) scal[z] = 1.0f / (s1[0] * s2[0]);
    } else {
        int h = bx - 144;
        for (int jj = t; jj < 512; jj += 256) {
            float s = 0.f, q = 0.f;
#pragma unroll
            for (int b = 0; b < 2; ++b)
#pragma unroll
                for (int ti = 0; ti < 4; ++ti) {
                    int zz = b * 8 + h;
                    s += rsum[(zz * 4 + ti) * 512 + jj];
                    q += rsq [(zz * 4 + ti) * 512 + jj];
                }
            float m_ = s / 1024.f;
            float var = (q - s * s / 1024.f) / 1023.f;
            inv_sig[h * 512 + jj] = 1.0f / sqrtf(var + 1e-5f);
            mu[h * 512 + jj] = m_;
        }
    }
}

// ============ fg_k<MODE>: symmetric 512x512 fp16 GEMM, lower tiles only, mirror write ============
// MODE 0: T0 = -s * Wh@Wh^T (tri kend=col0+128).  MODE 1: T' = 2*V + T@T^T (full K).
template<int MODE>
__global__ __launch_bounds__(256) void fg_k(const _Float16* __restrict__ A,
                                            const _Float16* V,
                                            _Float16* __restrict__ R,
                                            const float* __restrict__ scal)
{
    const int tIs[10] = {0,1,1,2,2,2,3,3,3,3};
    const int tJs[10] = {0,0,1,0,1,2,0,1,2,3};
    __shared__ _Float16 As[128][40];
    __shared__ _Float16 Bs[128][40];
    const int z = blockIdx.y;
    const long zo = (long)z * Ss * Ss;
    const int row0 = tIs[blockIdx.x] * 128, col0 = tJs[blockIdx.x] * 128;
    const bool diag = (row0 == col0);
    const int kend = (MODE == 0) ? (col0 + 128) : Ss;
    const int t = threadIdx.x;
    const int wave = t >> 6, lane = t & 63;
    const int ln = lane & 15, quad = lane >> 4;
    const int wm = (wave & 1) * 64, wn = (wave >> 1) * 64;

    f32x4 acc[4][4];
#pragma unroll
    for (int i = 0; i < 4; ++i)
#pragma unroll
        for (int j = 0; j < 4; ++j)
            acc[i][j] = (f32x4){0.f, 0.f, 0.f, 0.f};

    const int r2 = t >> 1, c2 = (t & 1) * 16;
    const long aoff = zo + (long)(row0 + r2) * Ss;
    const long boff = zo + (long)(col0 + r2) * Ss;

    uint4 a0 = *(const uint4*)&A[aoff + c2];
    uint4 a1 = *(const uint4*)&A[aoff + c2 + 8];
    uint4 b0 = *(const uint4*)&A[boff + c2];
    uint4 b1 = *(const uint4*)&A[boff + c2 + 8];

    for (int k0 = 0; k0 < kend; k0 += 32) {
        *(uint4*)&As[r2][c2]     = a0;
        *(uint4*)&As[r2][c2 + 8] = a1;
        *(uint4*)&Bs[r2][c2]     = b0;
        *(uint4*)&Bs[r2][c2 + 8] = b1;
        __syncthreads();
        int kn = k0 + 32;
        if (kn < kend) {
            a0 = *(const uint4*)&A[aoff + kn + c2];
            a1 = *(const uint4*)&A[aoff + kn + c2 + 8];
            b0 = *(const uint4*)&A[boff + kn + c2];
            b1 = *(const uint4*)&A[boff + kn + c2 + 8];
        }
        f16x8 af[4], bf[4];
#pragma unroll
        for (int mt = 0; mt < 4; ++mt)
            af[mt] = *(const f16x8*)&As[wm + mt * 16 + ln][quad * 8];
#pragma unroll
        for (int nt = 0; nt < 4; ++nt)
            bf[nt] = *(const f16x8*)&Bs[wn + nt * 16 + ln][quad * 8];
#pragma unroll
        for (int mt = 0; mt < 4; ++mt)
#pragma unroll
            for (int nt = 0; nt < 4; ++nt)
                acc[mt][nt] = __builtin_amdgcn_mfma_f32_16x16x32_f16(af[mt], bf[nt], acc[mt][nt], 0, 0, 0);
        __syncthreads();
    }

    float s = (MODE == 0) ? scal[z] : 0.f;
#pragma unroll
    for (int mt = 0; mt < 4; ++mt) {
        const int gr0 = row0 + wm + mt * 16 + quad * 4;
#pragma unroll
        for (int nt = 0; nt < 4; ++nt) {
            const int gc = col0 + wn + nt * 16 + ln;
            _Float16 rb[4] __attribute__((aligned(8)));
#pragma unroll
            for (int r = 0; r < 4; ++r) {
                const long gi = zo + (long)(gr0 + r) * Ss + gc;
                float val;
                if (MODE == 0) val = -s * acc[mt][nt][r];
                else           val = 2.0f * (float)V[gi] + acc[mt][nt][r];
                _Float16 o = (_Float16)val;
                R[gi] = o;
                rb[r] = o;
            }
            if (!diag)   // mirror write: R[gc][gr0..gr0+3]
                *(uint2*)&R[zo + (long)gc * Ss + gr0] = *(const uint2*)rb;
        }
    }
}

// ============ wk_k<MODE>: wide 64x512 fp16 GEMM (pipelined core) ============
// MODE 1: Y' = 2*V + Y x T (full K). MODE 2: c2sT = inv_sig[n]*s*(Y x Wt) (kbeg=col0) + negoffs.
template<int MODE>
__global__ __launch_bounds__(256) void wk_k(const _Float16* __restrict__ A,
                                            const _Float16* __restrict__ B,
                                            const _Float16* V,
                                            _Float16* __restrict__ R,
                                            const float* __restrict__ scal,
                                            const float* __restrict__ inv_sig,
                                            const float* __restrict__ mu,
                                            float* __restrict__ negopart)
{
    __shared__ __align__(16) char sm[10240];
    __shared__ float red[64];
    const int z = blockIdx.y;
    const int h = z & 7;
    const int col0 = blockIdx.x * 64;
    const long zA = (long)z * (HD * Ss);
    const long zB = (long)z * Ss * Ss;
    const int kbeg = (MODE == 1) ? 0 : col0;
    const int t = threadIdx.x;
    const int wave = t >> 6, lane = t & 63;
    const int ln = lane & 15, quad = lane >> 4;

    f32x4 acc[4];
#pragma unroll
    for (int i = 0; i < 4; ++i) acc[i] = (f32x4){0.f, 0.f, 0.f, 0.f};

    wk_core(sm, A, B, zA, zB, col0, kbeg, Ss, acc);

    if (MODE == 2) {
        if (t < 64) red[t] = 0.f;
        __syncthreads();
    }
    const int gr = wave * 16 + quad * 4;
    float pr[4] = {0.f, 0.f, 0.f, 0.f};
    float s = (MODE == 2) ? scal[z] : 0.f;
#pragma unroll
    for (int nt = 0; nt < 4; ++nt) {
        const int gc = col0 + nt * 16 + ln;
#pragma unroll
        for (int r = 0; r < 4; ++r) {
            const int d = gr + r;
            float val;
            if (MODE == 1) val = 2.0f * (float)V[zA + (long)d * Ss + gc] + acc[nt][r];
            else {
                val = inv_sig[h * 512 + gc] * (s * acc[nt][r]);
                pr[r] += mu[h * 512 + gc] * val;
            }
            R[zA + (long)d * Ss + gc] = (_Float16)val;
        }
    }
    if (MODE == 2) {
#pragma unroll
        for (int r = 0; r < 4; ++r)
            atomicAdd(&red[gr + r], pr[r]);
        __syncthreads();
        if (t < 64)
            negopart[(z * 8 + blockIdx.x) * 64 + t] = red[t];
    }
}

// ============ ga_k: gat = Wh @ c2s - neg, fp32 out in [B,S,DIM] ============
__global__ __launch_bounds__(256) void ga_k(const _Float16* __restrict__ Wh,
                                            const _Float16* __restrict__ c2sT,
                                            const float* __restrict__ negopart,
                                            float* __restrict__ gat)
{
    __shared__ __align__(16) char sm[10240];
    __shared__ float neg[64];
    const int z = blockIdx.y;
    const int b = z >> 3, h = z & 7;
    const int m0 = blockIdx.x * 64;
    const long zA = (long)z * Ss * Ss;
    const long zB = (long)z * (HD * Ss);
    const int t = threadIdx.x;
    const int wave = t >> 6, lane = t & 63;
    const int ln = lane & 15, quad = lane >> 4;

    if (t < 64) {
        float s = 0.f;
#pragma unroll
        for (int k = 0; k < 8; ++k) s += negopart[(z * 8 + k) * 64 + t];
        neg[t] = s;
    }
    __syncthreads();

    // reuse wk_core with A=c2sT (64 x K), B=Wh rows m0..m0+63 (K<=m0+64), swap roles:
    // gat[m][d] = sum_k Wh[m][k] c2sT[d][k]  ->  treat A=c2sT zA, B=Wh zB, col0=m0
    f32x4 acc[4];
#pragma unroll
    for (int i = 0; i < 4; ++i) acc[i] = (f32x4){0.f, 0.f, 0.f, 0.f};
    wk_core(sm, c2sT, Wh, zB, zA, m0, 0, m0 + 64, acc);

    const int gr = wave * 16 + quad * 4;   // d index
#pragma unroll
    for (int nt = 0; nt < 4; ++nt) {
        const int m = m0 + nt * 16 + ln;
#pragma unroll
        for (int r = 0; r < 4; ++r) {
            const int d = gr + r;
            gat[(long)b * (Ss * DIM) + (long)m * DIM + h * HD + d] = acc[nt][r] - neg[d];
        }
    }
}

extern "C" void kernel_launch(void* const* d_in, const int* in_sizes, int n_in,
                              void* d_out, int out_size, void* d_ws, size_t ws_size,
                              hipStream_t stream)
{
    const float* x      = (const float*)d_in[0];
    const float* qkv_w  = (const float*)d_in[1];
    const float* qkv_b  = (const float*)d_in[2];
    const float* proj_w = (const float*)d_in[3];
    const float* proj_b = (const float*)d_in[4];
    float* out = (float*)d_out;
    float* ws  = (float*)d_ws;

    float* qkv     = ws;                                   // 1,572,864 f
    _Float16* Wh   = (_Float16*)(ws + 1572864);            // 2,097,152 f
    _Float16* Wt   = (_Float16*)(ws + 3670016);            // 2,097,152 f
    _Float16* vT   = (_Float16*)(ws + 5767168);            //   262,144 f
    _Float16* T[5];
    for (int i = 0; i < 5; ++i) T[i] = (_Float16*)(ws + 6029312 + (long)i * 2097152);
    _Float16* Ya   = (_Float16*)(ws + 16515072);
    _Float16* Yb   = (_Float16*)(ws + 16777216);
    _Float16* c2sT = (_Float16*)(ws + 17039360);
    float* rsum    = ws + 17301504;
    float* rsq     = ws + 17334272;
    float* csum    = ws + 17367040;
    float* scal    = ws + 17399808;
    float* mu      = ws + 17399824;
    float* inv_sig = ws + 17403920;
    float* negp    = ws + 17408016;
    float* gat     = ws + 17416208;

    dim3 blk(256);

    // 1. qkv = x @ qkv_w^T + qkv_b
    mm_k<<<dim3(12, 8), blk, 0, stream>>>(x, qkv_w, qkv_b, qkv, DIM, 3 * DIM);

    // 2. W fp16 (both layouts) + reduction partials + vT
    wt_fused<<<dim3(18, 16), blk, 0, stream>>>(qkv, Wh, Wt, vT, rsum, rsq, csum);

    // 3. ctxT = vT x Wt  ||  scale + whitening stats   (independent; one dispatch)
    mid_k<<<dim3(152), blk, 0, stream>>>(vT, Wt, Ya, rsum, rsq, csum, scal, mu, inv_sig);

    // 4. T0 = -s * W W^T  (symmetric, lower tiles + mirror)
    fg_k<0><<<dim3(10, 16), blk, 0, stream>>>(Wh, nullptr, T[0], scal);

    // 5-8. residual squarings: T' = 2T + T^2  (symmetric)
    for (int i = 0; i < 4; ++i)
        fg_k<1><<<dim3(10, 16), blk, 0, stream>>>(T[i], T[i], T[i + 1], nullptr);

    // 9-13. y^T <- 2 y^T + y^T T_k, k = 4..0
    _Float16* yc = Ya;
    _Float16* yn = Yb;
    for (int k = 4; k >= 0; --k) {
        wk_k<1><<<dim3(8, 16), blk, 0, stream>>>(yc, T[k], yc, yn, nullptr, nullptr, nullptr, nullptr);
        _Float16* tmp = yc; yc = yn; yn = tmp;
    }

    // 14. c2sT = inv_sig * s * (y^T W) + negoff partials
    wk_k<2><<<dim3(8, 16), blk, 0, stream>>>(yc, Wt, nullptr, c2sT, scal, inv_sig, mu, negp);

    // 15. gat = W @ c2s - neg
    ga_k<<<dim3(8, 16), blk, 0, stream>>>(Wh, c2sT, negp, gat);

    // 16. out = gat @ proj_w^T + proj_b
    mm_k<<<dim3(4, 8), blk, 0, stream>>>(gat, proj_w, proj_b, out, DIM, DIM);
}